// Round 2
// 560.389 us; speedup vs baseline: 1.1931x; 1.1931x over previous
//
#include <hip/hip_runtime.h>
#include <math.h>

#define NPOOL 4096
#define NSEQ  512
#define NF    20
#define EDIM  64
#define GDIM  128
#define SDIM  16
#define ALPH  20
#define SPLITK 16
#define KSLICE (NPOOL / SPLITK)   // 256

__device__ __forceinline__ double relu_d(double x){ return x > 0.0 ? x : 0.0; }
__device__ __forceinline__ double sigm_d(double x){ return 1.0 / (1.0 + exp(-x)); }

// Fin[i][e] = f @ w_feat + b_feat (f64); R = relu(Fin)
__global__ __launch_bounds__(256) void k_prep(const float* __restrict__ f, const float* __restrict__ wf,
                       const float* __restrict__ bf, double* __restrict__ Fin, double* __restrict__ R) {
    int t = blockIdx.x * 256 + threadIdx.x;   // NPOOL*EDIM
    int i = t >> 6, e = t & 63;
    double acc = (double)bf[e];
#pragma unroll
    for (int j = 0; j < NF; ++j)
        acc += (double)f[i * NF + j] * (double)wf[j * EDIM + e];
    Fin[t] = acc;
    R[t] = acc > 0.0 ? acc : 0.0;
}

// seq_embed = x @ w_seq + b_seq (f64)
__global__ __launch_bounds__(256) void k_seqe(const float* __restrict__ x, const float* __restrict__ wsq,
                       const float* __restrict__ bsq, double* __restrict__ seqe) {
    int t = blockIdx.x * 256 + threadIdx.x;   // NSEQ*SDIM = 8192
    int k = t >> 4, s = t & 15;
    double acc = (double)bsq[s];
#pragma unroll
    for (int q = 0; q < ALPH; ++q)
        acc += (double)x[k * ALPH + q] * (double)wsq[q * SDIM + s];
    seqe[t] = acc;
}

__global__ __launch_bounds__(256) void k_zero(double* __restrict__ buf) {
    buf[(size_t)blockIdx.x * 256 + threadIdx.x] = 0.0;
}

// C(4096x64 f64) += A(4096x4096 f32) @ B(4096x64 f64), split-K, VALU f64 FMA.
// 256 threads, 4x4 register tile with STRIDE-16 ownership:
// thread (tx=t&15, ty=t>>4) owns rows {ty+16i}, cols {tx+16j}.
// LDS reads: As[kk][ty+16i] -> 4 broadcast addrs/wave (conflict-free);
//            Bs[kk][tx+16j] -> 16 distinct even banks, 4-lane broadcast (conflict-free).
// Row pad 65 (130 mod 32 = 2) -> staging writes at worst 2-way (free).
__global__ __launch_bounds__(256, 4) void gemm_f64_v2(const float* __restrict__ A, const double* __restrict__ B,
                                                      double* __restrict__ C) {
    __shared__ double As[32][65];   // [k][row]
    __shared__ double Bs[32][65];   // [k][col]
    int t  = threadIdx.x;
    int tx = t & 15;
    int ty = t >> 4;
    int row0 = blockIdx.x * 64;
    int k0   = blockIdx.y * KSLICE;
    double acc[4][4] = {};
    for (int kt = k0; kt < k0 + KSLICE; kt += 32) {
        // stage A: 64 rows x 32 k (f32 -> f64), transposed to [k][row]
        {
            int r = t >> 2, kq = t & 3;
            const float* Ap = A + (size_t)(row0 + r) * NPOOL + kt + kq * 8;
            float4 f0 = *(const float4*)Ap;
            float4 f1 = *(const float4*)(Ap + 4);
            int kb = kq * 8;
            As[kb + 0][r] = (double)f0.x; As[kb + 1][r] = (double)f0.y;
            As[kb + 2][r] = (double)f0.z; As[kb + 3][r] = (double)f0.w;
            As[kb + 4][r] = (double)f1.x; As[kb + 5][r] = (double)f1.y;
            As[kb + 6][r] = (double)f1.z; As[kb + 7][r] = (double)f1.w;
        }
        // stage B: 32 k-rows x 64 cols (contiguous 512B per instruction)
#pragma unroll
        for (int it = 0; it < 8; ++it) {
            int l = t + 256 * it;
            int kr = l >> 6, cc = l & 63;
            Bs[kr][cc] = B[(size_t)(kt + kr) * 64 + cc];
        }
        __syncthreads();
#pragma unroll
        for (int kk = 0; kk < 32; ++kk) {
            double a0 = As[kk][ty +  0];
            double a1 = As[kk][ty + 16];
            double a2 = As[kk][ty + 32];
            double a3 = As[kk][ty + 48];
            double b0 = Bs[kk][tx +  0];
            double b1 = Bs[kk][tx + 16];
            double b2 = Bs[kk][tx + 32];
            double b3 = Bs[kk][tx + 48];
            acc[0][0] = fma(a0, b0, acc[0][0]); acc[0][1] = fma(a0, b1, acc[0][1]);
            acc[0][2] = fma(a0, b2, acc[0][2]); acc[0][3] = fma(a0, b3, acc[0][3]);
            acc[1][0] = fma(a1, b0, acc[1][0]); acc[1][1] = fma(a1, b1, acc[1][1]);
            acc[1][2] = fma(a1, b2, acc[1][2]); acc[1][3] = fma(a1, b3, acc[1][3]);
            acc[2][0] = fma(a2, b0, acc[2][0]); acc[2][1] = fma(a2, b1, acc[2][1]);
            acc[2][2] = fma(a2, b2, acc[2][2]); acc[2][3] = fma(a2, b3, acc[2][3]);
            acc[3][0] = fma(a3, b0, acc[3][0]); acc[3][1] = fma(a3, b1, acc[3][1]);
            acc[3][2] = fma(a3, b2, acc[3][2]); acc[3][3] = fma(a3, b3, acc[3][3]);
        }
        __syncthreads();
    }
#pragma unroll
    for (int i = 0; i < 4; ++i)
#pragma unroll
        for (int j = 0; j < 4; ++j)
            unsafeAtomicAdd(&C[(size_t)(row0 + ty + 16 * i) * 64 + tx + 16 * j], acc[i][j]);
}

// s[i] = relu(T3[i,:] @ w_gcn1) . w_edge[0:64]   (one wave per row)
__global__ __launch_bounds__(256) void k_head(const double* __restrict__ T3, const float* __restrict__ w1,
                       const float* __restrict__ we, double* __restrict__ s) {
    int row = (blockIdx.x * 256 + threadIdx.x) >> 6;
    int e = threadIdx.x & 63;
    const double* r = T3 + (size_t)row * 64;
    double h = 0.0;
#pragma unroll
    for (int c = 0; c < 64; ++c)
        h += r[c] * (double)w1[c * 64 + e];
    double p = (h > 0.0 ? h : 0.0) * (double)we[e];
    for (int off = 32; off; off >>= 1) p += __shfl_down(p, off, 64);
    if (e == 0) s[row] = p;
}

// full bitonic sort of 4096 (desc by key, asc by index on ties); also emits orderB
__global__ __launch_bounds__(1024) void k_sort(const double* __restrict__ s, int* __restrict__ order,
                        double* __restrict__ skey, int* __restrict__ orderB) {
    __shared__ double key[NPOOL];
    __shared__ int    idx[NPOOL];
    for (int t = threadIdx.x; t < NPOOL; t += 1024) { key[t] = s[t]; idx[t] = t; }
    __syncthreads();
    for (int k = 2; k <= NPOOL; k <<= 1) {
        for (int j = k >> 1; j > 0; j >>= 1) {
            for (int t = threadIdx.x; t < NPOOL; t += 1024) {
                int l = t ^ j;
                if (l > t) {
                    double ka = key[t], kb = key[l];
                    int ia = idx[t], ib = idx[l];
                    bool aLess = (ka > kb) || (ka == kb && ia < ib);
                    bool asc = ((t & k) == 0);
                    bool doSwap = asc ? !aLess : aLess;
                    if (doSwap) { key[t] = kb; key[l] = ka; idx[t] = ib; idx[l] = ia; }
                }
            }
            __syncthreads();
        }
    }
    for (int t = threadIdx.x; t < NSEQ; t += 1024) {
        order[t] = idx[t]; skey[t] = key[t]; orderB[t] = idx[0];
    }
}

// per-k parallel recurrence pieces for a given selection sequence `order`
__global__ __launch_bounds__(256) void k_perk(const double* __restrict__ Fin, const int* __restrict__ order,
                       const float* __restrict__ w2, const float* __restrict__ wgr, const float* __restrict__ bgr,
                       const float* __restrict__ wga, const float* __restrict__ bga,
                       double* __restrict__ phi_inf, double* __restrict__ phi_pair, double* __restrict__ hlast) {
    const double r2 = 0.70710678118654752440;
    const double r3 = 0.57735026918962576451;
    __shared__ double u[4][64];
    __shared__ double comb[3][64];
    __shared__ double v[3][64];
    __shared__ double hgg[3][2][GDIM];
    int k = blockIdx.x;
    int t = threadIdx.x;
    {
        int w = t >> 6, e = t & 63;
        int j = k - 3 + w;
        u[w][e] = (j >= 0) ? Fin[(size_t)order[j] * 64 + e] : 0.0;
    }
    __syncthreads();
    if (t < 192) {
        int w = t >> 6, e = t & 63;
        double dh_km3 = (k - 3 == 0) ? r2 : r3;
        double dh_km2 = (k - 2 == 0) ? r2 : r3;
        double dh_km1 = (k - 1 == 0) ? r2 : r3;
        double outer, c0, c1, c2, c3;
        if (w == 0) {        // v_{k-2} (final form)
            outer = dh_km2; c0 = dh_km3; c1 = dh_km2; c2 = dh_km1; c3 = 0.0;
        } else if (w == 1) { // v_{k-1}^{(k)}
            outer = dh_km1; c0 = 0.0; c1 = dh_km2; c2 = dh_km1; c3 = r2;
        } else {             // v_k^{(k)}
            if (k == 0) { outer = 1.0; c0 = c1 = c2 = 0.0; c3 = 1.0; }
            else        { outer = r2;  c0 = c1 = 0.0; c2 = dh_km1; c3 = r2; }
        }
        comb[w][e] = outer * (c0 * u[0][e] + c1 * u[1][e] + c2 * u[2][e] + c3 * u[3][e]);
    }
    __syncthreads();
    if (t < 192) {
        int w = t >> 6, e = t & 63;
        double acc = 0.0;
#pragma unroll
        for (int j = 0; j < 64; ++j)
            acc += comb[w][j] * (double)w2[j * 64 + e];
        v[w][e] = acc;
    }
    __syncthreads();
    for (int rep = 0; rep < 3; ++rep) {
        int d = t & 127, g = t >> 7;
        const float* W = g ? wga : wgr;
        const float* B = g ? bga : bgr;
        double acc = (double)B[d];
#pragma unroll
        for (int j = 0; j < 64; ++j)
            acc += v[rep][j] * (double)W[j * GDIM + d];
        hgg[rep][g][d] = acc;
    }
    __syncthreads();
    if (t < 128) {
        if (k >= 2) phi_inf[(size_t)(k - 2) * GDIM + t] = hgg[0][0][t] * sigm_d(hgg[0][1][t]);
        double pp = hgg[2][0][t] * sigm_d(hgg[2][1][t]);
        if (k >= 1) pp += hgg[1][0][t] * sigm_d(hgg[1][1][t]);
        phi_pair[(size_t)k * GDIM + t] = pp;
    } else if (t < 192) {
        hlast[(size_t)k * 64 + (t - 128)] = v[2][t - 128];
    }
}

// per-dim prefix scan: hgr[k] = sum_{j<=k-2} phi_inf[j] + phi_pair[k]
__global__ __launch_bounds__(512) void k_scan(const double* __restrict__ phi_inf, const double* __restrict__ phi_pair,
                       double* __restrict__ hgr) {
    __shared__ double sb[NSEQ];
    int d = blockIdx.x, t = threadIdx.x;
    sb[t] = (t >= 2) ? phi_inf[(size_t)(t - 2) * GDIM + d] : 0.0;
    for (int off = 1; off < NSEQ; off <<= 1) {
        __syncthreads();
        double add = (t >= off) ? sb[t - off] : 0.0;
        __syncthreads();
        sb[t] += add;
    }
    __syncthreads();
    hgr[(size_t)t * GDIM + d] = sb[t] + phi_pair[(size_t)t * GDIM + d];
}

// c_k from carried (k-1) state; one wave per k
__global__ __launch_bounds__(64) void k_c(const double* __restrict__ hlast, const double* __restrict__ hgr,
                   const double* __restrict__ seqe, const float* __restrict__ we, double* __restrict__ c) {
    int k = blockIdx.x, j = threadIdx.x;
    double ts = 0.0;
    if (k > 0) {
        ts += relu_d(hlast[(size_t)(k - 1) * 64 + j]) * (double)we[64 + j];
        ts += relu_d(hgr[(size_t)(k - 1) * GDIM + j]) * (double)we[144 + j];
        ts += relu_d(hgr[(size_t)(k - 1) * GDIM + 64 + j]) * (double)we[208 + j];
    }
    if (j < 16) ts += relu_d(seqe[(size_t)k * SDIM + j]) * (double)we[128 + j];
    for (int off = 32; off; off >>= 1) ts += __shfl_down(ts, off, 64);
    if (j == 0) c[k] = ts;
}

// regime A valid iff skey[t] + cA[t] > 0 for all t>=1
__global__ __launch_bounds__(512) void k_verifyA(const double* __restrict__ skey, const double* __restrict__ cA,
                         int* __restrict__ flagA) {
    __shared__ int bad;
    int t = threadIdx.x;
    if (t == 0) bad = 0;
    __syncthreads();
    if (t >= 1 && !(skey[t] + cA[t] > 0.0)) atomicOr(&bad, 1);
    __syncthreads();
    if (t == 0) flagA[0] = bad;
}

// regime B valid iff skey[1] + cB[k] <= 0 for all k>=1
__global__ __launch_bounds__(512) void k_verifyB(const double* __restrict__ skey, const double* __restrict__ cB,
                         int* __restrict__ flagB) {
    __shared__ int bad;
    int t = threadIdx.x;
    if (t == 0) bad = 0;
    __syncthreads();
    if (t >= 1 && (skey[1] + cB[t] > 0.0)) atomicOr(&bad, 1);
    __syncthreads();
    if (t == 0) flagB[0] = bad;
}

// pick regime: mode 0 = advance (A), 1 = repeat (B), 2 = fallback
__global__ __launch_bounds__(512) void k_select(const int* __restrict__ flagA, const int* __restrict__ flagB,
                        const double* __restrict__ cA, const double* __restrict__ cB,
                        const int* __restrict__ order, double* __restrict__ c,
                        int* __restrict__ idxs_sel, int* __restrict__ mode) {
    int t = threadIdx.x;
    if (flagA[0] == 0) {
        c[t] = cA[t]; idxs_sel[t] = order[t];
        if (t == 0) mode[0] = 0;
    } else if (flagB[0] == 0) {
        c[t] = cB[t]; idxs_sel[t] = order[0];
        if (t == 0) mode[0] = 1;
    } else {
        if (t == 0) mode[0] = 2;
    }
}

// exact sequential fallback (runs only when both fast paths invalid)
__global__ __launch_bounds__(256) void k_fallback(const int* __restrict__ mode,
        const double* __restrict__ Fin, const int* __restrict__ order, const double* __restrict__ skey,
        const double* __restrict__ seqe,
        const float* __restrict__ w2, const float* __restrict__ wgr, const float* __restrict__ bgr,
        const float* __restrict__ wga, const float* __restrict__ bga, const float* __restrict__ we,
        int* __restrict__ idxs_sel, double* __restrict__ c) {
    if (mode[0] != 2) return;
    const double r2 = 0.70710678118654752440;
    const double r3 = 0.57735026918962576451;
    __shared__ double u[4][64];
    __shared__ double comb[3][64];
    __shared__ double v[3][64];
    __shared__ double hgg[3][2][GDIM];
    __shared__ double Phi[GDIM], hgraph[GDIM], hlastS[64];
    __shared__ int selS, ptrS, minS_;
    int t = threadIdx.x;
    if (t < 64) { u[0][t] = u[1][t] = u[2][t] = u[3][t] = 0.0; hlastS[t] = 0.0; }
    if (t < 128) { Phi[t] = 0.0; hgraph[t] = 0.0; }
    if (t == 0) { ptrS = 0; minS_ = 0x7fffffff; }
    __syncthreads();
    for (int k = 0; k < NSEQ; ++k) {
        if (t < 64) {
            int j = t;
            double ts = relu_d(hlastS[j]) * (double)we[64 + j]
                      + relu_d(hgraph[j]) * (double)we[144 + j]
                      + relu_d(hgraph[64 + j]) * (double)we[208 + j];
            if (j < 16) ts += relu_d(seqe[(size_t)k * SDIM + j]) * (double)we[128 + j];
            for (int off = 32; off; off >>= 1) ts += __shfl_down(ts, off, 64);
            if (j == 0) {
                c[k] = ts;
                int ptr = ptrS, idx;
                if (ptr == 0) { idx = order[0]; minS_ = idx; ptrS = 1; }
                else if (skey[ptr] + ts > 0.0) {
                    idx = order[ptr];
                    if (idx < minS_) minS_ = idx;
                    ptrS = ptr + 1;
                } else idx = minS_;
                selS = idx;
                idxs_sel[k] = idx;
            }
        }
        __syncthreads();
        int idx = selS;
        if (t < 64) u[k & 3][t] = Fin[(size_t)idx * 64 + t];
        __syncthreads();
        if (t < 192) {
            int w = t >> 6, e = t & 63;
            double dh_km3 = (k - 3 == 0) ? r2 : r3;
            double dh_km2 = (k - 2 == 0) ? r2 : r3;
            double dh_km1 = (k - 1 == 0) ? r2 : r3;
            double outer, c0, c1, c2, c3;
            if (w == 0) {
                outer = dh_km2; c0 = dh_km3; c1 = dh_km2; c2 = dh_km1; c3 = 0.0;
            } else if (w == 1) {
                outer = dh_km1; c0 = 0.0; c1 = dh_km2; c2 = dh_km1; c3 = r2;
            } else {
                if (k == 0) { outer = 1.0; c0 = c1 = c2 = 0.0; c3 = 1.0; }
                else        { outer = r2;  c0 = c1 = 0.0; c2 = dh_km1; c3 = r2; }
            }
            double uu0 = u[(k - 3) & 3][e], uu1 = u[(k - 2) & 3][e], uu2 = u[(k - 1) & 3][e], uu3 = u[k & 3][e];
            comb[w][e] = outer * (c0 * uu0 + c1 * uu1 + c2 * uu2 + c3 * uu3);
        }
        __syncthreads();
        if (t < 192) {
            int w = t >> 6, e = t & 63;
            double acc = 0.0;
#pragma unroll
            for (int j = 0; j < 64; ++j)
                acc += comb[w][j] * (double)w2[j * 64 + e];
            v[w][e] = acc;
        }
        __syncthreads();
        for (int rep = 0; rep < 3; ++rep) {
            int d = t & 127, g = t >> 7;
            const float* W = g ? wga : wgr;
            const float* B = g ? bga : bgr;
            double acc = (double)B[d];
#pragma unroll
            for (int j = 0; j < 64; ++j)
                acc += v[rep][j] * (double)W[j * GDIM + d];
            hgg[rep][g][d] = acc;
        }
        __syncthreads();
        if (t < 128) {
            if (k >= 2) Phi[t] += hgg[0][0][t] * sigm_d(hgg[0][1][t]);
            double hg = Phi[t] + hgg[2][0][t] * sigm_d(hgg[2][1][t]);
            if (k >= 1) hg += hgg[1][0][t] * sigm_d(hgg[1][1][t]);
            hgraph[t] = hg;
        } else if (t < 192) {
            hlastS[t - 128] = v[2][t - 128];
        }
        __syncthreads();
    }
}

__global__ __launch_bounds__(256) void k_rank_init(int* __restrict__ rank) {
    rank[blockIdx.x * 256 + threadIdx.x] = 1 << 30;
}

__global__ __launch_bounds__(256) void k_rank_set(const int* __restrict__ idxs_sel, int* __restrict__ rank,
                           float* __restrict__ out) {
    int t = blockIdx.x * 256 + threadIdx.x;
    if (t < NSEQ) {
        atomicMin(&rank[idxs_sel[t]], t);
        out[(size_t)NSEQ * NPOOL + t] = (float)idxs_sel[t];
    }
}

__global__ __launch_bounds__(256) void k_fill(const double* __restrict__ s, const double* __restrict__ c,
                       const int* __restrict__ rank, const float* __restrict__ be, float* __restrict__ out) {
    size_t t = (size_t)blockIdx.x * 256 + threadIdx.x;   // NSEQ*NPOOL
    int k = (int)(t >> 12);
    int i = (int)(t & 4095);
    double bed = (double)be[0];
    bool masked = rank[i] < k;
    out[t] = masked ? (float)bed : (float)(s[i] + c[k] + bed);
}

extern "C" void kernel_launch(void* const* d_in, const int* in_sizes, int n_in,
                              void* d_out, int out_size, void* d_ws, size_t ws_size,
                              hipStream_t stream) {
    const float* x    = (const float*)d_in[0];
    const float* f    = (const float*)d_in[1];
    const float* amat = (const float*)d_in[2];
    const float* dmat = (const float*)d_in[3];
    const float* wf   = (const float*)d_in[4];
    const float* bf   = (const float*)d_in[5];
    const float* w1   = (const float*)d_in[6];
    const float* w2   = (const float*)d_in[7];
    const float* wgr  = (const float*)d_in[8];
    const float* bgr  = (const float*)d_in[9];
    const float* wga  = (const float*)d_in[10];
    const float* bga  = (const float*)d_in[11];
    const float* we   = (const float*)d_in[12];
    const float* be   = (const float*)d_in[13];
    const float* wsq  = (const float*)d_in[14];
    const float* bsq  = (const float*)d_in[15];
    float* out = (float*)d_out;

    char* p = (char*)d_ws;
    const size_t BIG = (size_t)NPOOL * 64 * sizeof(double);   // 2 MB
    double* BUF0 = (double*)p; p += BIG;       // R, then t2
    double* Fin  = (double*)p; p += BIG;
    double* BUF2 = (double*)p; p += BIG;       // t1, then t3
    double* seqe = (double*)p; p += (size_t)NSEQ * SDIM * sizeof(double);
    double* s    = (double*)p; p += (size_t)NPOOL * sizeof(double);
    double* skey = (double*)p; p += (size_t)NSEQ * sizeof(double);
    double* phi_inf  = (double*)p; p += (size_t)NSEQ * GDIM * sizeof(double);
    double* phi_pair = (double*)p; p += (size_t)NSEQ * GDIM * sizeof(double);
    double* hgr   = (double*)p; p += (size_t)NSEQ * GDIM * sizeof(double);
    double* hlast = (double*)p; p += (size_t)NSEQ * 64 * sizeof(double);
    double* cA    = (double*)p; p += (size_t)NSEQ * sizeof(double);
    double* cB    = (double*)p; p += (size_t)NSEQ * sizeof(double);
    double* c     = (double*)p; p += (size_t)NSEQ * sizeof(double);
    int* order    = (int*)p; p += 2048;
    int* orderB   = (int*)p; p += 2048;
    int* idxs_sel = (int*)p; p += 2048;
    int* rank     = (int*)p; p += (size_t)NPOOL * sizeof(int);
    int* flagA    = (int*)p; p += 256;
    int* flagB    = (int*)p; p += 256;
    int* mode     = (int*)p; p += 256;

    double* R  = BUF0;
    double* T1 = BUF2;
    double* T2 = BUF0;   // alias: R dead after first GEMM
    double* T3 = BUF2;   // alias: T1 dead after second GEMM

    dim3 ggrid(NPOOL / 64, SPLITK);

    k_prep<<<1024, 256, 0, stream>>>(f, wf, bf, Fin, R);
    k_seqe<<<32, 256, 0, stream>>>(x, wsq, bsq, seqe);

    k_zero<<<1024, 256, 0, stream>>>(T1);
    gemm_f64_v2<<<ggrid, 256, 0, stream>>>(dmat, R, T1);    // t1 = d @ R
    k_zero<<<1024, 256, 0, stream>>>(T2);
    gemm_f64_v2<<<ggrid, 256, 0, stream>>>(amat, T1, T2);   // t2 = a @ t1
    k_zero<<<1024, 256, 0, stream>>>(T3);
    gemm_f64_v2<<<ggrid, 256, 0, stream>>>(dmat, T2, T3);   // t3 = d @ t2

    k_head<<<NPOOL / 4, 256, 0, stream>>>(T3, w1, we, s);
    k_sort<<<1, 1024, 0, stream>>>(s, order, skey, orderB);

    // hypothesis A: selection follows sorted order
    k_perk<<<NSEQ, 256, 0, stream>>>(Fin, order, w2, wgr, bgr, wga, bga, phi_inf, phi_pair, hlast);
    k_scan<<<GDIM, 512, 0, stream>>>(phi_inf, phi_pair, hgr);
    k_c<<<NSEQ, 64, 0, stream>>>(hlast, hgr, seqe, we, cA);
    k_verifyA<<<1, 512, 0, stream>>>(skey, cA, flagA);

    // hypothesis B: step 0 picks order[0], every later step re-picks it
    k_perk<<<NSEQ, 256, 0, stream>>>(Fin, orderB, w2, wgr, bgr, wga, bga, phi_inf, phi_pair, hlast);
    k_scan<<<GDIM, 512, 0, stream>>>(phi_inf, phi_pair, hgr);
    k_c<<<NSEQ, 64, 0, stream>>>(hlast, hgr, seqe, we, cB);
    k_verifyB<<<1, 512, 0, stream>>>(skey, cB, flagB);

    k_select<<<1, 512, 0, stream>>>(flagA, flagB, cA, cB, order, c, idxs_sel, mode);
    k_fallback<<<1, 256, 0, stream>>>(mode, Fin, order, skey, seqe, w2, wgr, bgr, wga, bga, we, idxs_sel, c);

    k_rank_init<<<NPOOL / 256, 256, 0, stream>>>(rank);
    k_rank_set<<<2, 256, 0, stream>>>(idxs_sel, rank, out);
    k_fill<<<(NSEQ * NPOOL) / 256, 256, 0, stream>>>(s, c, rank, be, out);
}

// Round 3
// 525.710 us; speedup vs baseline: 1.2718x; 1.0660x over previous
//
#include <hip/hip_runtime.h>
#include <math.h>

#define NPOOL 4096
#define NSEQ  512
#define NF    20
#define EDIM  64
#define GDIM  128
#define SDIM  16
#define ALPH  20
#define SPLITK 16
#define KSLICE (NPOOL / SPLITK)   // 256

__device__ __forceinline__ double relu_d(double x){ return x > 0.0 ? x : 0.0; }
__device__ __forceinline__ double sigm_d(double x){ return 1.0 / (1.0 + exp(-x)); }

// Fin[i][e] = f @ w_feat + b_feat (f64); R = relu(Fin). Also zeroes T1 (same size).
__global__ __launch_bounds__(256) void k_prep(const float* __restrict__ f, const float* __restrict__ wf,
                       const float* __restrict__ bf, double* __restrict__ Fin, double* __restrict__ R,
                       double* __restrict__ T1z) {
    int t = blockIdx.x * 256 + threadIdx.x;   // NPOOL*EDIM
    int i = t >> 6, e = t & 63;
    double acc = (double)bf[e];
#pragma unroll
    for (int j = 0; j < NF; ++j)
        acc += (double)f[i * NF + j] * (double)wf[j * EDIM + e];
    Fin[t] = acc;
    R[t] = acc > 0.0 ? acc : 0.0;
    T1z[t] = 0.0;
}

// seq_embed = x @ w_seq + b_seq (f64). Also inits rank[].
__global__ __launch_bounds__(256) void k_seqe(const float* __restrict__ x, const float* __restrict__ wsq,
                       const float* __restrict__ bsq, double* __restrict__ seqe, int* __restrict__ rank) {
    int t = blockIdx.x * 256 + threadIdx.x;   // NSEQ*SDIM = 8192
    int k = t >> 4, s = t & 15;
    double acc = (double)bsq[s];
#pragma unroll
    for (int q = 0; q < ALPH; ++q)
        acc += (double)x[k * ALPH + q] * (double)wsq[q * SDIM + s];
    seqe[t] = acc;
    if (t < NPOOL) rank[t] = 1 << 30;
}

__global__ __launch_bounds__(256) void k_zero(double* __restrict__ buf) {
    buf[(size_t)blockIdx.x * 256 + threadIdx.x] = 0.0;
}

// C(4096x64 f64) += A(4096x4096 f32) @ B(4096x64 f64), split-K, VALU f64 FMA.
// 256 threads, 4x4 tile, PAIRED ownership: thread (tx,ty) owns rows {2ty,2ty+1,2ty+32,2ty+33},
// cols {2tx,2tx+1,2tx+32,2tx+33} -> LDS reads are 4x ds_read_b128 per 16 FMA:
//   A reads: only ty-dependent -> 4 distinct addresses/wave (broadcast, conflict-free)
//   B reads: tx 0..15, banks 4(kk+tx)%32 -> 2 addrs/bank (2-way = free per m136)
// Row pad 66 keeps every double2 16B-aligned (66*kk + 2t always even).
__global__ __launch_bounds__(256, 4) void gemm_f64_v3(const float* __restrict__ A, const double* __restrict__ B,
                                                      double* __restrict__ C) {
    __shared__ double As[32][66];   // [k][row]
    __shared__ double Bs[32][66];   // [k][col]
    int t  = threadIdx.x;
    int tx = t & 15;
    int ty = t >> 4;
    int row0 = blockIdx.x * 64;
    int k0   = blockIdx.y * KSLICE;
    double acc[4][4] = {};
    for (int kt = k0; kt < k0 + KSLICE; kt += 32) {
        // stage A: 64 rows x 32 k (f32 -> f64), transposed to [k][row]
        {
            int r = t >> 2, kq = t & 3;
            const float* Ap = A + (size_t)(row0 + r) * NPOOL + kt + kq * 8;
            float4 f0 = *(const float4*)Ap;
            float4 f1 = *(const float4*)(Ap + 4);
            int kb = kq * 8;
            As[kb + 0][r] = (double)f0.x; As[kb + 1][r] = (double)f0.y;
            As[kb + 2][r] = (double)f0.z; As[kb + 3][r] = (double)f0.w;
            As[kb + 4][r] = (double)f1.x; As[kb + 5][r] = (double)f1.y;
            As[kb + 6][r] = (double)f1.z; As[kb + 7][r] = (double)f1.w;
        }
        // stage B: 32 k-rows x 64 cols
#pragma unroll
        for (int it = 0; it < 8; ++it) {
            int l = t + 256 * it;
            int kr = l >> 6, cc = l & 63;
            Bs[kr][cc] = B[(size_t)(kt + kr) * 64 + cc];
        }
        __syncthreads();
#pragma unroll
        for (int kk = 0; kk < 32; ++kk) {
            double2 a01 = *(const double2*)&As[kk][2 * ty];
            double2 a23 = *(const double2*)&As[kk][2 * ty + 32];
            double2 b01 = *(const double2*)&Bs[kk][2 * tx];
            double2 b23 = *(const double2*)&Bs[kk][2 * tx + 32];
            double a[4] = {a01.x, a01.y, a23.x, a23.y};
            double b[4] = {b01.x, b01.y, b23.x, b23.y};
#pragma unroll
            for (int i = 0; i < 4; ++i)
#pragma unroll
                for (int j = 0; j < 4; ++j)
                    acc[i][j] = fma(a[i], b[j], acc[i][j]);
        }
        __syncthreads();
    }
    int rr[4] = {2 * ty, 2 * ty + 1, 2 * ty + 32, 2 * ty + 33};
    int cc[4] = {2 * tx, 2 * tx + 1, 2 * tx + 32, 2 * tx + 33};
#pragma unroll
    for (int i = 0; i < 4; ++i)
#pragma unroll
        for (int j = 0; j < 4; ++j)
            unsafeAtomicAdd(&C[(size_t)(row0 + rr[i]) * 64 + cc[j]], acc[i][j]);
}

// s[i] = relu(T3[i,:] @ w_gcn1) . w_edge[0:64]   (one wave per row)
__global__ __launch_bounds__(256) void k_head(const double* __restrict__ T3, const float* __restrict__ w1,
                       const float* __restrict__ we, double* __restrict__ s) {
    int row = (blockIdx.x * 256 + threadIdx.x) >> 6;
    int e = threadIdx.x & 63;
    const double* r = T3 + (size_t)row * 64;
    double h = 0.0;
#pragma unroll
    for (int c = 0; c < 64; ++c)
        h += r[c] * (double)w1[c * 64 + e];
    double p = (h > 0.0 ? h : 0.0) * (double)we[e];
    for (int off = 32; off; off >>= 1) p += __shfl_down(p, off, 64);
    if (e == 0) s[row] = p;
}

// Top-512 selection: radix-select exact 512th-largest key T over sortable-u64,
// compact {>T} U {==T}, bitonic-sort 1024 candidates by (key desc, idx asc).
// Guards provably detect any wrong T / tie overflow -> full bitonic-4096 fallback.
__global__ __launch_bounds__(1024) void k_sort2(const double* __restrict__ s, int* __restrict__ order,
                        double* __restrict__ skey, int* __restrict__ orderB) {
    __shared__ unsigned long long keys[NPOOL];   // 32 KB
    __shared__ int idxs[NPOOL];                  // 16 KB (fallback)
    __shared__ unsigned long long ck[1024];      // 8 KB
    __shared__ int ci[1024];                     // 4 KB
    __shared__ unsigned int hist[256];
    __shared__ unsigned int cntHi, cntEq;
    __shared__ unsigned long long prefix_s;
    __shared__ int K_s, fb_s;
    int t = threadIdx.x;
    for (int i = t; i < NPOOL; i += 1024) {
        double v = s[i] + 0.0;                   // canonicalize -0 -> +0
        unsigned long long b = (unsigned long long)__double_as_longlong(v);
        unsigned long long m = (b >> 63) ? ~0ULL : 0x8000000000000000ULL;
        keys[i] = b ^ m;                         // order-preserving: bigger double -> bigger u64
        idxs[i] = i;
    }
    if (t == 0) { prefix_s = 0ULL; K_s = NSEQ; fb_s = 0; cntHi = 0; cntEq = 0; }
    __syncthreads();
    // radix select (MSB-first bytes): find T = NSEQ-th largest key
    for (int shift = 56; shift >= 0; shift -= 8) {
        if (t < 256) hist[t] = 0;
        __syncthreads();
        unsigned long long pre = prefix_s;
        unsigned long long hmask = (shift == 56) ? 0ULL : (~0ULL << (shift + 8));
        for (int i = t; i < NPOOL; i += 1024) {
            unsigned long long kv = keys[i];
            if ((kv & hmask) == pre)
                atomicAdd(&hist[(unsigned)(kv >> shift) & 255u], 1u);
        }
        __syncthreads();
        if (t == 0) {
            int K = K_s;
            int cum = 0, b = 255;
            for (; b >= 0; --b) { cum += (int)hist[b]; if (cum >= K) break; }
            if (b < 0) { fb_s = 1; b = 0; }      // inconsistent -> fallback
            K_s = K - (cum - (int)hist[b]);
            prefix_s |= ((unsigned long long)(unsigned)b << shift);
        }
        __syncthreads();
    }
    unsigned long long T = prefix_s;
    // compact candidates: first {>T}, then {==T}
    for (int i = t; i < NPOOL; i += 1024) {
        unsigned long long kv = keys[i];
        if (kv > T) {
            unsigned p = atomicAdd(&cntHi, 1u);
            if (p < 1024u) { ck[p] = kv; ci[p] = i; }
        }
    }
    __syncthreads();
    unsigned base = cntHi;
    for (int i = t; i < NPOOL; i += 1024) {
        if (keys[i] == T) {
            unsigned p = atomicAdd(&cntEq, 1u);
            if (base + p < 1024u) { ck[base + p] = T; ci[base + p] = i; }
        }
    }
    __syncthreads();
    // guards: cntHi must be < NSEQ; total candidates in [NSEQ, 1024]
    if (t == 0) {
        unsigned tot = cntHi + cntEq;
        if (cntHi >= (unsigned)NSEQ || tot < (unsigned)NSEQ || tot > 1024u) fb_s = 1;
    }
    __syncthreads();
    if (fb_s == 0) {
        // pad + bitonic sort 1024 candidates (desc key, asc idx on ties)
        unsigned tot = cntHi + cntEq;
        for (int i = (int)tot + t; i < 1024; i += 1024) { ck[i] = 0ULL; ci[i] = 0x7fffffff; }
        __syncthreads();
        for (int k2 = 2; k2 <= 1024; k2 <<= 1) {
            for (int j = k2 >> 1; j > 0; j >>= 1) {
                int l = t ^ j;
                if (l > t) {
                    unsigned long long ka = ck[t], kb = ck[l];
                    int ia = ci[t], ib = ci[l];
                    bool aBefore = (ka > kb) || (ka == kb && ia < ib);
                    bool asc = ((t & k2) == 0);
                    if (asc ? !aBefore : aBefore) { ck[t] = kb; ck[l] = ka; ci[t] = ib; ci[l] = ia; }
                }
                __syncthreads();
            }
        }
        if (t < NSEQ) {
            int id = ci[t];
            order[t] = id; skey[t] = s[id]; orderB[t] = ci[0];
        }
    } else {
        // full bitonic-4096 fallback on (sortable key, idx) — same ordering semantics
        for (int k2 = 2; k2 <= NPOOL; k2 <<= 1) {
            for (int j = k2 >> 1; j > 0; j >>= 1) {
                for (int tt = t; tt < NPOOL; tt += 1024) {
                    int l = tt ^ j;
                    if (l > tt) {
                        unsigned long long ka = keys[tt], kb = keys[l];
                        int ia = idxs[tt], ib = idxs[l];
                        bool aBefore = (ka > kb) || (ka == kb && ia < ib);
                        bool asc = ((tt & k2) == 0);
                        if (asc ? !aBefore : aBefore) { keys[tt] = kb; keys[l] = ka; idxs[tt] = ib; idxs[l] = ia; }
                    }
                }
                __syncthreads();
            }
        }
        for (int tt = t; tt < NSEQ; tt += 1024) {
            int id = idxs[tt];
            order[tt] = id; skey[tt] = s[id]; orderB[tt] = idxs[0];
        }
    }
}

// per-k recurrence pieces for BOTH hypotheses (which = blockIdx.x>>9): A uses orderA, B uses orderB
__global__ __launch_bounds__(256) void k_perk2(const double* __restrict__ Fin, const int* __restrict__ orderA,
                       const int* __restrict__ orderBv,
                       const float* __restrict__ w2, const float* __restrict__ wgr, const float* __restrict__ bgr,
                       const float* __restrict__ wga, const float* __restrict__ bga,
                       double* __restrict__ phi_inf, double* __restrict__ phi_pair, double* __restrict__ hlast) {
    const double r2 = 0.70710678118654752440;
    const double r3 = 0.57735026918962576451;
    __shared__ double u[4][64];
    __shared__ double comb[3][64];
    __shared__ double v[3][64];
    __shared__ double hgg[3][2][GDIM];
    int which = blockIdx.x >> 9;
    int k = blockIdx.x & (NSEQ - 1);
    const int* order = which ? orderBv : orderA;
    double* pi = phi_inf  + (size_t)which * NSEQ * GDIM;
    double* pp = phi_pair + (size_t)which * NSEQ * GDIM;
    double* hl = hlast    + (size_t)which * NSEQ * 64;
    int t = threadIdx.x;
    {
        int w = t >> 6, e = t & 63;
        int j = k - 3 + w;
        u[w][e] = (j >= 0) ? Fin[(size_t)order[j] * 64 + e] : 0.0;
    }
    __syncthreads();
    if (t < 192) {
        int w = t >> 6, e = t & 63;
        double dh_km3 = (k - 3 == 0) ? r2 : r3;
        double dh_km2 = (k - 2 == 0) ? r2 : r3;
        double dh_km1 = (k - 1 == 0) ? r2 : r3;
        double outer, c0, c1, c2, c3;
        if (w == 0) {        // v_{k-2} (final form)
            outer = dh_km2; c0 = dh_km3; c1 = dh_km2; c2 = dh_km1; c3 = 0.0;
        } else if (w == 1) { // v_{k-1}^{(k)}
            outer = dh_km1; c0 = 0.0; c1 = dh_km2; c2 = dh_km1; c3 = r2;
        } else {             // v_k^{(k)}
            if (k == 0) { outer = 1.0; c0 = c1 = c2 = 0.0; c3 = 1.0; }
            else        { outer = r2;  c0 = c1 = 0.0; c2 = dh_km1; c3 = r2; }
        }
        comb[w][e] = outer * (c0 * u[0][e] + c1 * u[1][e] + c2 * u[2][e] + c3 * u[3][e]);
    }
    __syncthreads();
    if (t < 192) {
        int w = t >> 6, e = t & 63;
        double acc = 0.0;
#pragma unroll
        for (int j = 0; j < 64; ++j)
            acc += comb[w][j] * (double)w2[j * 64 + e];
        v[w][e] = acc;
    }
    __syncthreads();
    for (int rep = 0; rep < 3; ++rep) {
        int d = t & 127, g = t >> 7;
        const float* W = g ? wga : wgr;
        const float* B = g ? bga : bgr;
        double acc = (double)B[d];
#pragma unroll
        for (int j = 0; j < 64; ++j)
            acc += v[rep][j] * (double)W[j * GDIM + d];
        hgg[rep][g][d] = acc;
    }
    __syncthreads();
    if (t < 128) {
        if (k >= 2) pi[(size_t)(k - 2) * GDIM + t] = hgg[0][0][t] * sigm_d(hgg[0][1][t]);
        double ppv = hgg[2][0][t] * sigm_d(hgg[2][1][t]);
        if (k >= 1) ppv += hgg[1][0][t] * sigm_d(hgg[1][1][t]);
        pp[(size_t)k * GDIM + t] = ppv;
    } else if (t < 192) {
        hl[(size_t)k * 64 + (t - 128)] = v[2][t - 128];
    }
}

// per-dim prefix scan for both hypotheses: hgr[k] = sum_{j<=k-2} phi_inf[j] + phi_pair[k]
__global__ __launch_bounds__(512) void k_scan2(const double* __restrict__ phi_inf, const double* __restrict__ phi_pair,
                       double* __restrict__ hgr) {
    __shared__ double sb[NSEQ];
    int which = blockIdx.x >> 7;
    int d = blockIdx.x & (GDIM - 1), t = threadIdx.x;
    const double* pi = phi_inf  + (size_t)which * NSEQ * GDIM;
    const double* pp = phi_pair + (size_t)which * NSEQ * GDIM;
    double* hg = hgr + (size_t)which * NSEQ * GDIM;
    sb[t] = (t >= 2) ? pi[(size_t)(t - 2) * GDIM + d] : 0.0;
    for (int off = 1; off < NSEQ; off <<= 1) {
        __syncthreads();
        double add = (t >= off) ? sb[t - off] : 0.0;
        __syncthreads();
        sb[t] += add;
    }
    __syncthreads();
    hg[(size_t)t * GDIM + d] = sb[t] + pp[(size_t)t * GDIM + d];
}

// c_k for both hypotheses; one wave per (which, k)
__global__ __launch_bounds__(64) void k_c2(const double* __restrict__ hlast, const double* __restrict__ hgr,
                   const double* __restrict__ seqe, const float* __restrict__ we,
                   double* __restrict__ cA, double* __restrict__ cB) {
    int which = blockIdx.x >> 9;
    int k = blockIdx.x & (NSEQ - 1), j = threadIdx.x;
    const double* hl = hlast + (size_t)which * NSEQ * 64;
    const double* hg = hgr   + (size_t)which * NSEQ * GDIM;
    double* c = which ? cB : cA;
    double ts = 0.0;
    if (k > 0) {
        ts += relu_d(hl[(size_t)(k - 1) * 64 + j]) * (double)we[64 + j];
        ts += relu_d(hg[(size_t)(k - 1) * GDIM + j]) * (double)we[144 + j];
        ts += relu_d(hg[(size_t)(k - 1) * GDIM + 64 + j]) * (double)we[208 + j];
    }
    if (j < 16) ts += relu_d(seqe[(size_t)k * SDIM + j]) * (double)we[128 + j];
    for (int off = 32; off; off >>= 1) ts += __shfl_down(ts, off, 64);
    if (j == 0) c[k] = ts;
}

// block 0: regime A valid iff skey[t]+cA[t] > 0 for all t>=1
// block 1: regime B valid iff skey[1]+cB[k] <= 0 for all k>=1
__global__ __launch_bounds__(512) void k_verify2(const double* __restrict__ skey, const double* __restrict__ cA,
                         const double* __restrict__ cB, int* __restrict__ flagA, int* __restrict__ flagB) {
    __shared__ int bad;
    int t = threadIdx.x;
    if (t == 0) bad = 0;
    __syncthreads();
    if (blockIdx.x == 0) {
        if (t >= 1 && !(skey[t] + cA[t] > 0.0)) atomicOr(&bad, 1);
        __syncthreads();
        if (t == 0) flagA[0] = bad;
    } else {
        if (t >= 1 && (skey[1] + cB[t] > 0.0)) atomicOr(&bad, 1);
        __syncthreads();
        if (t == 0) flagB[0] = bad;
    }
}

// pick regime: mode 0 = advance (A), 1 = repeat (B), 2 = fallback
__global__ __launch_bounds__(512) void k_select(const int* __restrict__ flagA, const int* __restrict__ flagB,
                        const double* __restrict__ cA, const double* __restrict__ cB,
                        const int* __restrict__ order, double* __restrict__ c,
                        int* __restrict__ idxs_sel, int* __restrict__ mode) {
    int t = threadIdx.x;
    if (flagA[0] == 0) {
        c[t] = cA[t]; idxs_sel[t] = order[t];
        if (t == 0) mode[0] = 0;
    } else if (flagB[0] == 0) {
        c[t] = cB[t]; idxs_sel[t] = order[0];
        if (t == 0) mode[0] = 1;
    } else {
        if (t == 0) mode[0] = 2;
    }
}

// exact sequential fallback (runs only when both fast paths invalid)
__global__ __launch_bounds__(256) void k_fallback(const int* __restrict__ mode,
        const double* __restrict__ Fin, const int* __restrict__ order, const double* __restrict__ skey,
        const double* __restrict__ seqe,
        const float* __restrict__ w2, const float* __restrict__ wgr, const float* __restrict__ bgr,
        const float* __restrict__ wga, const float* __restrict__ bga, const float* __restrict__ we,
        int* __restrict__ idxs_sel, double* __restrict__ c) {
    if (mode[0] != 2) return;
    const double r2 = 0.70710678118654752440;
    const double r3 = 0.57735026918962576451;
    __shared__ double u[4][64];
    __shared__ double comb[3][64];
    __shared__ double v[3][64];
    __shared__ double hgg[3][2][GDIM];
    __shared__ double Phi[GDIM], hgraph[GDIM], hlastS[64];
    __shared__ int selS, ptrS, minS_;
    int t = threadIdx.x;
    if (t < 64) { u[0][t] = u[1][t] = u[2][t] = u[3][t] = 0.0; hlastS[t] = 0.0; }
    if (t < 128) { Phi[t] = 0.0; hgraph[t] = 0.0; }
    if (t == 0) { ptrS = 0; minS_ = 0x7fffffff; }
    __syncthreads();
    for (int k = 0; k < NSEQ; ++k) {
        if (t < 64) {
            int j = t;
            double ts = relu_d(hlastS[j]) * (double)we[64 + j]
                      + relu_d(hgraph[j]) * (double)we[144 + j]
                      + relu_d(hgraph[64 + j]) * (double)we[208 + j];
            if (j < 16) ts += relu_d(seqe[(size_t)k * SDIM + j]) * (double)we[128 + j];
            for (int off = 32; off; off >>= 1) ts += __shfl_down(ts, off, 64);
            if (j == 0) {
                c[k] = ts;
                int ptr = ptrS, idx;
                if (ptr == 0) { idx = order[0]; minS_ = idx; ptrS = 1; }
                else if (skey[ptr] + ts > 0.0) {
                    idx = order[ptr];
                    if (idx < minS_) minS_ = idx;
                    ptrS = ptr + 1;
                } else idx = minS_;
                selS = idx;
                idxs_sel[k] = idx;
            }
        }
        __syncthreads();
        int idx = selS;
        if (t < 64) u[k & 3][t] = Fin[(size_t)idx * 64 + t];
        __syncthreads();
        if (t < 192) {
            int w = t >> 6, e = t & 63;
            double dh_km3 = (k - 3 == 0) ? r2 : r3;
            double dh_km2 = (k - 2 == 0) ? r2 : r3;
            double dh_km1 = (k - 1 == 0) ? r2 : r3;
            double outer, c0, c1, c2, c3;
            if (w == 0) {
                outer = dh_km2; c0 = dh_km3; c1 = dh_km2; c2 = dh_km1; c3 = 0.0;
            } else if (w == 1) {
                outer = dh_km1; c0 = 0.0; c1 = dh_km2; c2 = dh_km1; c3 = r2;
            } else {
                if (k == 0) { outer = 1.0; c0 = c1 = c2 = 0.0; c3 = 1.0; }
                else        { outer = r2;  c0 = c1 = 0.0; c2 = dh_km1; c3 = r2; }
            }
            double uu0 = u[(k - 3) & 3][e], uu1 = u[(k - 2) & 3][e], uu2 = u[(k - 1) & 3][e], uu3 = u[k & 3][e];
            comb[w][e] = outer * (c0 * uu0 + c1 * uu1 + c2 * uu2 + c3 * uu3);
        }
        __syncthreads();
        if (t < 192) {
            int w = t >> 6, e = t & 63;
            double acc = 0.0;
#pragma unroll
            for (int j = 0; j < 64; ++j)
                acc += comb[w][j] * (double)w2[j * 64 + e];
            v[w][e] = acc;
        }
        __syncthreads();
        for (int rep = 0; rep < 3; ++rep) {
            int d = t & 127, g = t >> 7;
            const float* W = g ? wga : wgr;
            const float* B = g ? bga : bgr;
            double acc = (double)B[d];
#pragma unroll
            for (int j = 0; j < 64; ++j)
                acc += v[rep][j] * (double)W[j * GDIM + d];
            hgg[rep][g][d] = acc;
        }
        __syncthreads();
        if (t < 128) {
            if (k >= 2) Phi[t] += hgg[0][0][t] * sigm_d(hgg[0][1][t]);
            double hg = Phi[t] + hgg[2][0][t] * sigm_d(hgg[2][1][t]);
            if (k >= 1) hg += hgg[1][0][t] * sigm_d(hgg[1][1][t]);
            hgraph[t] = hg;
        } else if (t < 192) {
            hlastS[t - 128] = v[2][t - 128];
        }
        __syncthreads();
    }
}

__global__ __launch_bounds__(256) void k_rank_set(const int* __restrict__ idxs_sel, int* __restrict__ rank,
                           float* __restrict__ out) {
    int t = blockIdx.x * 256 + threadIdx.x;
    if (t < NSEQ) {
        atomicMin(&rank[idxs_sel[t]], t);
        out[(size_t)NSEQ * NPOOL + t] = (float)idxs_sel[t];
    }
}

__global__ __launch_bounds__(256) void k_fill(const double* __restrict__ s, const double* __restrict__ c,
                       const int* __restrict__ rank, const float* __restrict__ be, float* __restrict__ out) {
    size_t t = (size_t)blockIdx.x * 256 + threadIdx.x;   // NSEQ*NPOOL
    int k = (int)(t >> 12);
    int i = (int)(t & 4095);
    double bed = (double)be[0];
    bool masked = rank[i] < k;
    out[t] = masked ? (float)bed : (float)(s[i] + c[k] + bed);
}

extern "C" void kernel_launch(void* const* d_in, const int* in_sizes, int n_in,
                              void* d_out, int out_size, void* d_ws, size_t ws_size,
                              hipStream_t stream) {
    const float* x    = (const float*)d_in[0];
    const float* f    = (const float*)d_in[1];
    const float* amat = (const float*)d_in[2];
    const float* dmat = (const float*)d_in[3];
    const float* wf   = (const float*)d_in[4];
    const float* bf   = (const float*)d_in[5];
    const float* w1   = (const float*)d_in[6];
    const float* w2   = (const float*)d_in[7];
    const float* wgr  = (const float*)d_in[8];
    const float* bgr  = (const float*)d_in[9];
    const float* wga  = (const float*)d_in[10];
    const float* bga  = (const float*)d_in[11];
    const float* we   = (const float*)d_in[12];
    const float* be   = (const float*)d_in[13];
    const float* wsq  = (const float*)d_in[14];
    const float* bsq  = (const float*)d_in[15];
    float* out = (float*)d_out;

    char* p = (char*)d_ws;
    const size_t BIG = (size_t)NPOOL * 64 * sizeof(double);   // 2 MB
    double* BUF0 = (double*)p; p += BIG;       // R, then t2
    double* Fin  = (double*)p; p += BIG;
    double* BUF2 = (double*)p; p += BIG;       // t1, then t3
    double* seqe = (double*)p; p += (size_t)NSEQ * SDIM * sizeof(double);
    double* s    = (double*)p; p += (size_t)NPOOL * sizeof(double);
    double* skey = (double*)p; p += (size_t)NSEQ * sizeof(double);
    double* phi_inf  = (double*)p; p += 2 * (size_t)NSEQ * GDIM * sizeof(double);
    double* phi_pair = (double*)p; p += 2 * (size_t)NSEQ * GDIM * sizeof(double);
    double* hgr   = (double*)p; p += 2 * (size_t)NSEQ * GDIM * sizeof(double);
    double* hlast = (double*)p; p += 2 * (size_t)NSEQ * 64 * sizeof(double);
    double* cA    = (double*)p; p += (size_t)NSEQ * sizeof(double);
    double* cB    = (double*)p; p += (size_t)NSEQ * sizeof(double);
    double* c     = (double*)p; p += (size_t)NSEQ * sizeof(double);
    int* order    = (int*)p; p += 2048;
    int* orderB   = (int*)p; p += 2048;
    int* idxs_sel = (int*)p; p += 2048;
    int* rank     = (int*)p; p += (size_t)NPOOL * sizeof(int);
    int* flagA    = (int*)p; p += 256;
    int* flagB    = (int*)p; p += 256;
    int* mode     = (int*)p; p += 256;

    double* R  = BUF0;
    double* T1 = BUF2;
    double* T2 = BUF0;   // alias: R dead after first GEMM
    double* T3 = BUF2;   // alias: T1 dead after second GEMM

    dim3 ggrid(NPOOL / 64, SPLITK);

    k_prep<<<1024, 256, 0, stream>>>(f, wf, bf, Fin, R, T1);   // also zeroes T1
    k_seqe<<<32, 256, 0, stream>>>(x, wsq, bsq, seqe, rank);   // also inits rank

    gemm_f64_v3<<<ggrid, 256, 0, stream>>>(dmat, R, T1);    // t1 = d @ R
    k_zero<<<1024, 256, 0, stream>>>(T2);
    gemm_f64_v3<<<ggrid, 256, 0, stream>>>(amat, T1, T2);   // t2 = a @ t1
    k_zero<<<1024, 256, 0, stream>>>(T3);
    gemm_f64_v3<<<ggrid, 256, 0, stream>>>(dmat, T2, T3);   // t3 = d @ t2

    k_head<<<NPOOL / 4, 256, 0, stream>>>(T3, w1, we, s);
    k_sort2<<<1, 1024, 0, stream>>>(s, order, skey, orderB);

    // both hypotheses fused (A: sorted order; B: repeat order[0])
    k_perk2<<<2 * NSEQ, 256, 0, stream>>>(Fin, order, orderB, w2, wgr, bgr, wga, bga, phi_inf, phi_pair, hlast);
    k_scan2<<<2 * GDIM, 512, 0, stream>>>(phi_inf, phi_pair, hgr);
    k_c2<<<2 * NSEQ, 64, 0, stream>>>(hlast, hgr, seqe, we, cA, cB);
    k_verify2<<<2, 512, 0, stream>>>(skey, cA, cB, flagA, flagB);

    k_select<<<1, 512, 0, stream>>>(flagA, flagB, cA, cB, order, c, idxs_sel, mode);
    k_fallback<<<1, 256, 0, stream>>>(mode, Fin, order, skey, seqe, w2, wgr, bgr, wga, bga, we, idxs_sel, c);

    k_rank_set<<<2, 256, 0, stream>>>(idxs_sel, rank, out);
    k_fill<<<(NSEQ * NPOOL) / 256, 256, 0, stream>>>(s, c, rank, be, out);
}

// Round 4
// 467.294 us; speedup vs baseline: 1.4308x; 1.1250x over previous
//
#include <hip/hip_runtime.h>
#include <math.h>

#define NPOOL 4096
#define NSEQ  512
#define NF    20
#define EDIM  64
#define GDIM  128
#define SDIM  16
#define ALPH  20
#define SPLITK 16
#define KSLICE (NPOOL / SPLITK)   // 256

__device__ __forceinline__ double relu_d(double x){ return x > 0.0 ? x : 0.0; }
__device__ __forceinline__ double sigm_d(double x){ return 1.0 / (1.0 + exp(-x)); }

__device__ __forceinline__ unsigned long long sortable_u64(double x) {
    x = x + 0.0;                                  // canonicalize -0 -> +0
    unsigned long long b = (unsigned long long)__double_as_longlong(x);
    return b ^ ((b >> 63) ? ~0ULL : 0x8000000000000000ULL);
}

// Fin[i][e] = f @ w_feat + b_feat (f64); R = relu(Fin). Also zeroes T1 (same size).
__global__ __launch_bounds__(256) void k_prep(const float* __restrict__ f, const float* __restrict__ wf,
                       const float* __restrict__ bf, double* __restrict__ Fin, double* __restrict__ R,
                       double* __restrict__ T1z) {
    int t = blockIdx.x * 256 + threadIdx.x;   // NPOOL*EDIM
    int i = t >> 6, e = t & 63;
    double acc = (double)bf[e];
#pragma unroll
    for (int j = 0; j < NF; ++j)
        acc += (double)f[i * NF + j] * (double)wf[j * EDIM + e];
    Fin[t] = acc;
    R[t] = acc > 0.0 ? acc : 0.0;
    T1z[t] = 0.0;
}

// seq_embed = x @ w_seq + b_seq (f64). Also inits rank[].
__global__ __launch_bounds__(256) void k_seqe(const float* __restrict__ x, const float* __restrict__ wsq,
                       const float* __restrict__ bsq, double* __restrict__ seqe, int* __restrict__ rank) {
    int t = blockIdx.x * 256 + threadIdx.x;   // NSEQ*SDIM = 8192
    int k = t >> 4, s = t & 15;
    double acc = (double)bsq[s];
#pragma unroll
    for (int q = 0; q < ALPH; ++q)
        acc += (double)x[k * ALPH + q] * (double)wsq[q * SDIM + s];
    seqe[t] = acc;
    if (t < NPOOL) rank[t] = 1 << 30;
}

__global__ __launch_bounds__(256) void k_zero(double* __restrict__ buf) {
    buf[(size_t)blockIdx.x * 256 + threadIdx.x] = 0.0;
}

// C(4096x64 f64) += A(4096x4096 f32) @ B(4096x64 f64), split-K, VALU f64 FMA.
// 256 threads, 4x4 tile, PAIRED ownership (rows/cols {2q,2q+1,2q+32,2q+33}).
__global__ __launch_bounds__(256, 4) void gemm_f64_v3(const float* __restrict__ A, const double* __restrict__ B,
                                                      double* __restrict__ C) {
    __shared__ double As[32][66];   // [k][row]
    __shared__ double Bs[32][66];   // [k][col]
    int t  = threadIdx.x;
    int tx = t & 15;
    int ty = t >> 4;
    int row0 = blockIdx.x * 64;
    int k0   = blockIdx.y * KSLICE;
    double acc[4][4] = {};
    for (int kt = k0; kt < k0 + KSLICE; kt += 32) {
        // stage A: 64 rows x 32 k (f32 -> f64), transposed to [k][row]
        {
            int r = t >> 2, kq = t & 3;
            const float* Ap = A + (size_t)(row0 + r) * NPOOL + kt + kq * 8;
            float4 f0 = *(const float4*)Ap;
            float4 f1 = *(const float4*)(Ap + 4);
            int kb = kq * 8;
            As[kb + 0][r] = (double)f0.x; As[kb + 1][r] = (double)f0.y;
            As[kb + 2][r] = (double)f0.z; As[kb + 3][r] = (double)f0.w;
            As[kb + 4][r] = (double)f1.x; As[kb + 5][r] = (double)f1.y;
            As[kb + 6][r] = (double)f1.z; As[kb + 7][r] = (double)f1.w;
        }
        // stage B: 32 k-rows x 64 cols
#pragma unroll
        for (int it = 0; it < 8; ++it) {
            int l = t + 256 * it;
            int kr = l >> 6, cc = l & 63;
            Bs[kr][cc] = B[(size_t)(kt + kr) * 64 + cc];
        }
        __syncthreads();
#pragma unroll
        for (int kk = 0; kk < 32; ++kk) {
            double2 a01 = *(const double2*)&As[kk][2 * ty];
            double2 a23 = *(const double2*)&As[kk][2 * ty + 32];
            double2 b01 = *(const double2*)&Bs[kk][2 * tx];
            double2 b23 = *(const double2*)&Bs[kk][2 * tx + 32];
            double a[4] = {a01.x, a01.y, a23.x, a23.y};
            double b[4] = {b01.x, b01.y, b23.x, b23.y};
#pragma unroll
            for (int i = 0; i < 4; ++i)
#pragma unroll
                for (int j = 0; j < 4; ++j)
                    acc[i][j] = fma(a[i], b[j], acc[i][j]);
        }
        __syncthreads();
    }
    int rr[4] = {2 * ty, 2 * ty + 1, 2 * ty + 32, 2 * ty + 33};
    int cc[4] = {2 * tx, 2 * tx + 1, 2 * tx + 32, 2 * tx + 33};
#pragma unroll
    for (int i = 0; i < 4; ++i)
#pragma unroll
        for (int j = 0; j < 4; ++j)
            unsafeAtomicAdd(&C[(size_t)(row0 + rr[i]) * 64 + cc[j]], acc[i][j]);
}

// s[i] = relu(T3[i,:] @ w_gcn1) . w_edge[0:64]   (one wave per row; w1 cached in LDS)
__global__ __launch_bounds__(256) void k_head(const double* __restrict__ T3, const float* __restrict__ w1,
                       const float* __restrict__ we, double* __restrict__ s) {
    __shared__ float w1s[64 * 64];
    int tt = threadIdx.x;
    for (int i = tt; i < 64 * 64; i += 256) w1s[i] = w1[i];
    __syncthreads();
    int row = (blockIdx.x * 256 + tt) >> 6;
    int e = tt & 63;
    const double* r = T3 + (size_t)row * 64;
    double h = 0.0;
#pragma unroll
    for (int c = 0; c < 64; ++c)
        h += r[c] * (double)w1s[c * 64 + e];
    double p = (h > 0.0 ? h : 0.0) * (double)we[e];
    for (int off = 32; off; off >>= 1) p += __shfl_down(p, off, 64);
    if (e == 0) s[row] = p;
}

// Full sort of 4096 keys (desc, idx asc on ties) via packed-u64 register bitonic:
// P = (~sortkey[63:12] << 12) | idx  -> ascending P == (key desc, idx asc).
// 4 elems/thread in regs; j=1,2 in-register; j=4..128 via __shfl_xor (no barriers);
// j>=256 via LDS (10 barrier rounds total). Truncation-tie guard -> exact fallback.
__global__ __launch_bounds__(1024) void k_sort3(const double* __restrict__ s, int* __restrict__ order,
                        double* __restrict__ skey, int* __restrict__ orderB) {
    __shared__ unsigned long long P[NPOOL];   // 32 KB
    __shared__ int idxF[NPOOL];               // 16 KB (fallback only)
    __shared__ int fbS;
    int t = threadIdx.x;
    if (t == 0) fbS = 0;
    unsigned long long v[4];
#pragma unroll
    for (int i = 0; i < 4; ++i) {
        int e = 4 * t + i;
        unsigned long long srt = sortable_u64(s[e]);
        v[i] = ((~(srt >> 12)) << 12) | (unsigned long long)e;
    }

#define SHFL_ROUND(jj, kk)                                                        \
    {                                                                             \
        int lm = (int)((jj) >> 2);                                                \
        _Pragma("unroll")                                                         \
        for (int i = 0; i < 4; ++i) {                                             \
            unsigned long long p = (unsigned long long)__shfl_xor((long long)v[i], lm, 64); \
            unsigned e = 4u * (unsigned)t + (unsigned)i;                          \
            bool takeMin = (((e & (jj)) == 0u) == ((e & (kk)) == 0u));            \
            unsigned long long mn = v[i] < p ? v[i] : p;                          \
            unsigned long long mx = v[i] < p ? p : v[i];                          \
            v[i] = takeMin ? mn : mx;                                             \
        }                                                                         \
    }

#define LOCAL_ROUNDS(kk)                                                          \
    {                                                                             \
        if ((kk) >= 4) {                                                          \
            _Pragma("unroll")                                                     \
            for (int i = 0; i < 2; ++i) {                                         \
                unsigned e = 4u * (unsigned)t + (unsigned)i;                      \
                bool asc = ((e & (kk)) == 0u);                                    \
                unsigned long long a = v[i], b = v[i + 2];                        \
                bool sw = asc ? (a > b) : (a < b);                                \
                v[i] = sw ? b : a; v[i + 2] = sw ? a : b;                         \
            }                                                                     \
        }                                                                         \
        _Pragma("unroll")                                                         \
        for (int i = 0; i < 4; i += 2) {                                          \
            unsigned e = 4u * (unsigned)t + (unsigned)i;                          \
            bool asc = ((e & (kk)) == 0u);                                        \
            unsigned long long a = v[i], b = v[i + 1];                            \
            bool sw = asc ? (a > b) : (a < b);                                    \
            v[i] = sw ? b : a; v[i + 1] = sw ? a : b;                             \
        }                                                                         \
    }

    // phase 1: k = 2..256 (purely intra-wave)
    for (unsigned k = 2; k <= 256; k <<= 1) {
        for (unsigned j = k >> 1; j >= 4; j >>= 1) SHFL_ROUND(j, k)
        LOCAL_ROUNDS(k)
    }
    // phase 2: k = 512..4096 (j>=256 via LDS, rest intra-wave)
    for (unsigned k = 512; k <= 4096; k <<= 1) {
        for (unsigned j = k >> 1; j >= 256; j >>= 1) {
            __syncthreads();
            P[4 * t + 0] = v[0]; P[4 * t + 1] = v[1];
            P[4 * t + 2] = v[2]; P[4 * t + 3] = v[3];
            __syncthreads();
            unsigned base = (4u * (unsigned)t) ^ j;
#pragma unroll
            for (int i = 0; i < 4; ++i) {
                unsigned e = 4u * (unsigned)t + (unsigned)i;
                unsigned long long p = P[base + i];
                bool takeMin = (((e & j) == 0u) == ((e & k) == 0u));
                unsigned long long mn = v[i] < p ? v[i] : p;
                unsigned long long mx = v[i] < p ? p : v[i];
                v[i] = takeMin ? mn : mx;
            }
        }
        for (unsigned j = 128; j >= 4; j >>= 1) SHFL_ROUND(j, k)
        LOCAL_ROUNDS(k)
    }
#undef SHFL_ROUND
#undef LOCAL_ROUNDS

    __syncthreads();
    P[4 * t + 0] = v[0]; P[4 * t + 1] = v[1];
    P[4 * t + 2] = v[2]; P[4 * t + 3] = v[3];
    __syncthreads();
    // truncation-tie guard over positions 0..512 (adjacent pairs)
    if (t < 512) {
        unsigned long long pa = P[t], pb = P[t + 1];
        if ((pa >> 12) == (pb >> 12)) {
            int ia = (int)(pa & 4095ULL), ib = (int)(pb & 4095ULL);
            if (sortable_u64(s[ia]) != sortable_u64(s[ib])) atomicOr(&fbS, 1);
        }
    }
    __syncthreads();
    if (fbS == 0) {
        if (t < NSEQ) {
            int id = (int)(P[t] & 4095ULL);
            order[t] = id; skey[t] = s[id]; orderB[t] = (int)(P[0] & 4095ULL);
        }
        return;
    }
    // exact fallback: full bitonic on (sortable64, idx)
    for (int i = t; i < NPOOL; i += 1024) { P[i] = sortable_u64(s[i]); idxF[i] = i; }
    __syncthreads();
    for (int k2 = 2; k2 <= NPOOL; k2 <<= 1) {
        for (int j = k2 >> 1; j > 0; j >>= 1) {
            for (int tt = t; tt < NPOOL; tt += 1024) {
                int l = tt ^ j;
                if (l > tt) {
                    unsigned long long ka = P[tt], kb = P[l];
                    int ia = idxF[tt], ib = idxF[l];
                    bool aBefore = (ka > kb) || (ka == kb && ia < ib);
                    bool asc = ((tt & k2) == 0);
                    if (asc ? !aBefore : aBefore) { P[tt] = kb; P[l] = ka; idxF[tt] = ib; idxF[l] = ia; }
                }
            }
            __syncthreads();
        }
    }
    for (int tt = t; tt < NSEQ; tt += 1024) {
        int id = idxF[tt];
        order[tt] = id; skey[tt] = s[id]; orderB[tt] = idxF[0];
    }
}

// per-k recurrence pieces for BOTH hypotheses (which = blockIdx.x>>9): A uses orderA, B uses orderB
__global__ __launch_bounds__(256) void k_perk2(const double* __restrict__ Fin, const int* __restrict__ orderA,
                       const int* __restrict__ orderBv,
                       const float* __restrict__ w2, const float* __restrict__ wgr, const float* __restrict__ bgr,
                       const float* __restrict__ wga, const float* __restrict__ bga,
                       double* __restrict__ phi_inf, double* __restrict__ phi_pair, double* __restrict__ hlast) {
    const double r2 = 0.70710678118654752440;
    const double r3 = 0.57735026918962576451;
    __shared__ double u[4][64];
    __shared__ double comb[3][64];
    __shared__ double v[3][64];
    __shared__ double hgg[3][2][GDIM];
    int which = blockIdx.x >> 9;
    int k = blockIdx.x & (NSEQ - 1);
    const int* order = which ? orderBv : orderA;
    double* pi = phi_inf  + (size_t)which * NSEQ * GDIM;
    double* pp = phi_pair + (size_t)which * NSEQ * GDIM;
    double* hl = hlast    + (size_t)which * NSEQ * 64;
    int t = threadIdx.x;
    {
        int w = t >> 6, e = t & 63;
        int j = k - 3 + w;
        u[w][e] = (j >= 0) ? Fin[(size_t)order[j] * 64 + e] : 0.0;
    }
    __syncthreads();
    if (t < 192) {
        int w = t >> 6, e = t & 63;
        double dh_km3 = (k - 3 == 0) ? r2 : r3;
        double dh_km2 = (k - 2 == 0) ? r2 : r3;
        double dh_km1 = (k - 1 == 0) ? r2 : r3;
        double outer, c0, c1, c2, c3;
        if (w == 0) {        // v_{k-2} (final form)
            outer = dh_km2; c0 = dh_km3; c1 = dh_km2; c2 = dh_km1; c3 = 0.0;
        } else if (w == 1) { // v_{k-1}^{(k)}
            outer = dh_km1; c0 = 0.0; c1 = dh_km2; c2 = dh_km1; c3 = r2;
        } else {             // v_k^{(k)}
            if (k == 0) { outer = 1.0; c0 = c1 = c2 = 0.0; c3 = 1.0; }
            else        { outer = r2;  c0 = c1 = 0.0; c2 = dh_km1; c3 = r2; }
        }
        comb[w][e] = outer * (c0 * u[0][e] + c1 * u[1][e] + c2 * u[2][e] + c3 * u[3][e]);
    }
    __syncthreads();
    if (t < 192) {
        int w = t >> 6, e = t & 63;
        double acc = 0.0;
#pragma unroll
        for (int j = 0; j < 64; ++j)
            acc += comb[w][j] * (double)w2[j * 64 + e];
        v[w][e] = acc;
    }
    __syncthreads();
    for (int rep = 0; rep < 3; ++rep) {
        int d = t & 127, g = t >> 7;
        const float* W = g ? wga : wgr;
        const float* B = g ? bga : bgr;
        double acc = (double)B[d];
#pragma unroll
        for (int j = 0; j < 64; ++j)
            acc += v[rep][j] * (double)W[j * GDIM + d];
        hgg[rep][g][d] = acc;
    }
    __syncthreads();
    if (t < 128) {
        if (k >= 2) pi[(size_t)(k - 2) * GDIM + t] = hgg[0][0][t] * sigm_d(hgg[0][1][t]);
        double ppv = hgg[2][0][t] * sigm_d(hgg[2][1][t]);
        if (k >= 1) ppv += hgg[1][0][t] * sigm_d(hgg[1][1][t]);
        pp[(size_t)k * GDIM + t] = ppv;
    } else if (t < 192) {
        hl[(size_t)k * 64 + (t - 128)] = v[2][t - 128];
    }
}

// per-dim prefix scan for both hypotheses: hgr[k] = sum_{j<=k-2} phi_inf[j] + phi_pair[k]
__global__ __launch_bounds__(512) void k_scan2(const double* __restrict__ phi_inf, const double* __restrict__ phi_pair,
                       double* __restrict__ hgr) {
    __shared__ double sb[NSEQ];
    int which = blockIdx.x >> 7;
    int d = blockIdx.x & (GDIM - 1), t = threadIdx.x;
    const double* pi = phi_inf  + (size_t)which * NSEQ * GDIM;
    const double* pp = phi_pair + (size_t)which * NSEQ * GDIM;
    double* hg = hgr + (size_t)which * NSEQ * GDIM;
    sb[t] = (t >= 2) ? pi[(size_t)(t - 2) * GDIM + d] : 0.0;
    for (int off = 1; off < NSEQ; off <<= 1) {
        __syncthreads();
        double add = (t >= off) ? sb[t - off] : 0.0;
        __syncthreads();
        sb[t] += add;
    }
    __syncthreads();
    hg[(size_t)t * GDIM + d] = sb[t] + pp[(size_t)t * GDIM + d];
}

// c_k for both hypotheses; one wave per (which, k)
__global__ __launch_bounds__(64) void k_c2(const double* __restrict__ hlast, const double* __restrict__ hgr,
                   const double* __restrict__ seqe, const float* __restrict__ we,
                   double* __restrict__ cA, double* __restrict__ cB) {
    int which = blockIdx.x >> 9;
    int k = blockIdx.x & (NSEQ - 1), j = threadIdx.x;
    const double* hl = hlast + (size_t)which * NSEQ * 64;
    const double* hg = hgr   + (size_t)which * NSEQ * GDIM;
    double* c = which ? cB : cA;
    double ts = 0.0;
    if (k > 0) {
        ts += relu_d(hl[(size_t)(k - 1) * 64 + j]) * (double)we[64 + j];
        ts += relu_d(hg[(size_t)(k - 1) * GDIM + j]) * (double)we[144 + j];
        ts += relu_d(hg[(size_t)(k - 1) * GDIM + 64 + j]) * (double)we[208 + j];
    }
    if (j < 16) ts += relu_d(seqe[(size_t)k * SDIM + j]) * (double)we[128 + j];
    for (int off = 32; off; off >>= 1) ts += __shfl_down(ts, off, 64);
    if (j == 0) c[k] = ts;
}

// block 0: regime A valid iff skey[t]+cA[t] > 0 for all t>=1
// block 1: regime B valid iff skey[1]+cB[k] <= 0 for all k>=1
__global__ __launch_bounds__(512) void k_verify2(const double* __restrict__ skey, const double* __restrict__ cA,
                         const double* __restrict__ cB, int* __restrict__ flagA, int* __restrict__ flagB) {
    __shared__ int bad;
    int t = threadIdx.x;
    if (t == 0) bad = 0;
    __syncthreads();
    if (blockIdx.x == 0) {
        if (t >= 1 && !(skey[t] + cA[t] > 0.0)) atomicOr(&bad, 1);
        __syncthreads();
        if (t == 0) flagA[0] = bad;
    } else {
        if (t >= 1 && (skey[1] + cB[t] > 0.0)) atomicOr(&bad, 1);
        __syncthreads();
        if (t == 0) flagB[0] = bad;
    }
}

// pick regime: mode 0 = advance (A), 1 = repeat (B), 2 = fallback
__global__ __launch_bounds__(512) void k_select(const int* __restrict__ flagA, const int* __restrict__ flagB,
                        const double* __restrict__ cA, const double* __restrict__ cB,
                        const int* __restrict__ order, double* __restrict__ c,
                        int* __restrict__ idxs_sel, int* __restrict__ mode) {
    int t = threadIdx.x;
    if (flagA[0] == 0) {
        c[t] = cA[t]; idxs_sel[t] = order[t];
        if (t == 0) mode[0] = 0;
    } else if (flagB[0] == 0) {
        c[t] = cB[t]; idxs_sel[t] = order[0];
        if (t == 0) mode[0] = 1;
    } else {
        if (t == 0) mode[0] = 2;
    }
}

// exact sequential fallback (runs only when both fast paths invalid)
__global__ __launch_bounds__(256) void k_fallback(const int* __restrict__ mode,
        const double* __restrict__ Fin, const int* __restrict__ order, const double* __restrict__ skey,
        const double* __restrict__ seqe,
        const float* __restrict__ w2, const float* __restrict__ wgr, const float* __restrict__ bgr,
        const float* __restrict__ wga, const float* __restrict__ bga, const float* __restrict__ we,
        int* __restrict__ idxs_sel, double* __restrict__ c) {
    if (mode[0] != 2) return;
    const double r2 = 0.70710678118654752440;
    const double r3 = 0.57735026918962576451;
    __shared__ double u[4][64];
    __shared__ double comb[3][64];
    __shared__ double v[3][64];
    __shared__ double hgg[3][2][GDIM];
    __shared__ double Phi[GDIM], hgraph[GDIM], hlastS[64];
    __shared__ int selS, ptrS, minS_;
    int t = threadIdx.x;
    if (t < 64) { u[0][t] = u[1][t] = u[2][t] = u[3][t] = 0.0; hlastS[t] = 0.0; }
    if (t < 128) { Phi[t] = 0.0; hgraph[t] = 0.0; }
    if (t == 0) { ptrS = 0; minS_ = 0x7fffffff; }
    __syncthreads();
    for (int k = 0; k < NSEQ; ++k) {
        if (t < 64) {
            int j = t;
            double ts = relu_d(hlastS[j]) * (double)we[64 + j]
                      + relu_d(hgraph[j]) * (double)we[144 + j]
                      + relu_d(hgraph[64 + j]) * (double)we[208 + j];
            if (j < 16) ts += relu_d(seqe[(size_t)k * SDIM + j]) * (double)we[128 + j];
            for (int off = 32; off; off >>= 1) ts += __shfl_down(ts, off, 64);
            if (j == 0) {
                c[k] = ts;
                int ptr = ptrS, idx;
                if (ptr == 0) { idx = order[0]; minS_ = idx; ptrS = 1; }
                else if (skey[ptr] + ts > 0.0) {
                    idx = order[ptr];
                    if (idx < minS_) minS_ = idx;
                    ptrS = ptr + 1;
                } else idx = minS_;
                selS = idx;
                idxs_sel[k] = idx;
            }
        }
        __syncthreads();
        int idx = selS;
        if (t < 64) u[k & 3][t] = Fin[(size_t)idx * 64 + t];
        __syncthreads();
        if (t < 192) {
            int w = t >> 6, e = t & 63;
            double dh_km3 = (k - 3 == 0) ? r2 : r3;
            double dh_km2 = (k - 2 == 0) ? r2 : r3;
            double dh_km1 = (k - 1 == 0) ? r2 : r3;
            double outer, c0, c1, c2, c3;
            if (w == 0) {
                outer = dh_km2; c0 = dh_km3; c1 = dh_km2; c2 = dh_km1; c3 = 0.0;
            } else if (w == 1) {
                outer = dh_km1; c0 = 0.0; c1 = dh_km2; c2 = dh_km1; c3 = r2;
            } else {
                if (k == 0) { outer = 1.0; c0 = c1 = c2 = 0.0; c3 = 1.0; }
                else        { outer = r2;  c0 = c1 = 0.0; c2 = dh_km1; c3 = r2; }
            }
            double uu0 = u[(k - 3) & 3][e], uu1 = u[(k - 2) & 3][e], uu2 = u[(k - 1) & 3][e], uu3 = u[k & 3][e];
            comb[w][e] = outer * (c0 * uu0 + c1 * uu1 + c2 * uu2 + c3 * uu3);
        }
        __syncthreads();
        if (t < 192) {
            int w = t >> 6, e = t & 63;
            double acc = 0.0;
#pragma unroll
            for (int j = 0; j < 64; ++j)
                acc += comb[w][j] * (double)w2[j * 64 + e];
            v[w][e] = acc;
        }
        __syncthreads();
        for (int rep = 0; rep < 3; ++rep) {
            int d = t & 127, g = t >> 7;
            const float* W = g ? wga : wgr;
            const float* B = g ? bga : bgr;
            double acc = (double)B[d];
#pragma unroll
            for (int j = 0; j < 64; ++j)
                acc += v[rep][j] * (double)W[j * GDIM + d];
            hgg[rep][g][d] = acc;
        }
        __syncthreads();
        if (t < 128) {
            if (k >= 2) Phi[t] += hgg[0][0][t] * sigm_d(hgg[0][1][t]);
            double hg = Phi[t] + hgg[2][0][t] * sigm_d(hgg[2][1][t]);
            if (k >= 1) hg += hgg[1][0][t] * sigm_d(hgg[1][1][t]);
            hgraph[t] = hg;
        } else if (t < 192) {
            hlastS[t - 128] = v[2][t - 128];
        }
        __syncthreads();
    }
}

__global__ __launch_bounds__(256) void k_rank_set(const int* __restrict__ idxs_sel, int* __restrict__ rank,
                           float* __restrict__ out) {
    int t = blockIdx.x * 256 + threadIdx.x;
    if (t < NSEQ) {
        atomicMin(&rank[idxs_sel[t]], t);
        out[(size_t)NSEQ * NPOOL + t] = (float)idxs_sel[t];
    }
}

__global__ __launch_bounds__(256) void k_fill(const double* __restrict__ s, const double* __restrict__ c,
                       const int* __restrict__ rank, const float* __restrict__ be, float* __restrict__ out) {
    size_t t = (size_t)blockIdx.x * 256 + threadIdx.x;   // NSEQ*NPOOL
    int k = (int)(t >> 12);
    int i = (int)(t & 4095);
    double bed = (double)be[0];
    bool masked = rank[i] < k;
    out[t] = masked ? (float)bed : (float)(s[i] + c[k] + bed);
}

extern "C" void kernel_launch(void* const* d_in, const int* in_sizes, int n_in,
                              void* d_out, int out_size, void* d_ws, size_t ws_size,
                              hipStream_t stream) {
    const float* x    = (const float*)d_in[0];
    const float* f    = (const float*)d_in[1];
    const float* amat = (const float*)d_in[2];
    const float* dmat = (const float*)d_in[3];
    const float* wf   = (const float*)d_in[4];
    const float* bf   = (const float*)d_in[5];
    const float* w1   = (const float*)d_in[6];
    const float* w2   = (const float*)d_in[7];
    const float* wgr  = (const float*)d_in[8];
    const float* bgr  = (const float*)d_in[9];
    const float* wga  = (const float*)d_in[10];
    const float* bga  = (const float*)d_in[11];
    const float* we   = (const float*)d_in[12];
    const float* be   = (const float*)d_in[13];
    const float* wsq  = (const float*)d_in[14];
    const float* bsq  = (const float*)d_in[15];
    float* out = (float*)d_out;

    char* p = (char*)d_ws;
    const size_t BIG = (size_t)NPOOL * 64 * sizeof(double);   // 2 MB
    double* BUF0 = (double*)p; p += BIG;       // R, then t2
    double* Fin  = (double*)p; p += BIG;
    double* BUF2 = (double*)p; p += BIG;       // t1, then t3
    double* seqe = (double*)p; p += (size_t)NSEQ * SDIM * sizeof(double);
    double* s    = (double*)p; p += (size_t)NPOOL * sizeof(double);
    double* skey = (double*)p; p += (size_t)NSEQ * sizeof(double);
    double* phi_inf  = (double*)p; p += 2 * (size_t)NSEQ * GDIM * sizeof(double);
    double* phi_pair = (double*)p; p += 2 * (size_t)NSEQ * GDIM * sizeof(double);
    double* hgr   = (double*)p; p += 2 * (size_t)NSEQ * GDIM * sizeof(double);
    double* hlast = (double*)p; p += 2 * (size_t)NSEQ * 64 * sizeof(double);
    double* cA    = (double*)p; p += (size_t)NSEQ * sizeof(double);
    double* cB    = (double*)p; p += (size_t)NSEQ * sizeof(double);
    double* c     = (double*)p; p += (size_t)NSEQ * sizeof(double);
    int* order    = (int*)p; p += 2048;
    int* orderB   = (int*)p; p += 2048;
    int* idxs_sel = (int*)p; p += 2048;
    int* rank     = (int*)p; p += (size_t)NPOOL * sizeof(int);
    int* flagA    = (int*)p; p += 256;
    int* flagB    = (int*)p; p += 256;
    int* mode     = (int*)p; p += 256;

    double* R  = BUF0;
    double* T1 = BUF2;
    double* T2 = BUF0;   // alias: R dead after first GEMM
    double* T3 = BUF2;   // alias: T1 dead after second GEMM

    dim3 ggrid(NPOOL / 64, SPLITK);

    k_prep<<<1024, 256, 0, stream>>>(f, wf, bf, Fin, R, T1);   // also zeroes T1
    k_seqe<<<32, 256, 0, stream>>>(x, wsq, bsq, seqe, rank);   // also inits rank

    gemm_f64_v3<<<ggrid, 256, 0, stream>>>(dmat, R, T1);    // t1 = d @ R
    k_zero<<<1024, 256, 0, stream>>>(T2);
    gemm_f64_v3<<<ggrid, 256, 0, stream>>>(amat, T1, T2);   // t2 = a @ t1
    k_zero<<<1024, 256, 0, stream>>>(T3);
    gemm_f64_v3<<<ggrid, 256, 0, stream>>>(dmat, T2, T3);   // t3 = d @ t2

    k_head<<<NPOOL / 4, 256, 0, stream>>>(T3, w1, we, s);
    k_sort3<<<1, 1024, 0, stream>>>(s, order, skey, orderB);

    // both hypotheses fused (A: sorted order; B: repeat order[0])
    k_perk2<<<2 * NSEQ, 256, 0, stream>>>(Fin, order, orderB, w2, wgr, bgr, wga, bga, phi_inf, phi_pair, hlast);
    k_scan2<<<2 * GDIM, 512, 0, stream>>>(phi_inf, phi_pair, hgr);
    k_c2<<<2 * NSEQ, 64, 0, stream>>>(hlast, hgr, seqe, we, cA, cB);
    k_verify2<<<2, 512, 0, stream>>>(skey, cA, cB, flagA, flagB);

    k_select<<<1, 512, 0, stream>>>(flagA, flagB, cA, cB, order, c, idxs_sel, mode);
    k_fallback<<<1, 256, 0, stream>>>(mode, Fin, order, skey, seqe, w2, wgr, bgr, wga, bga, we, idxs_sel, c);

    k_rank_set<<<2, 256, 0, stream>>>(idxs_sel, rank, out);
    k_fill<<<(NSEQ * NPOOL) / 256, 256, 0, stream>>>(s, c, rank, be, out);
}